// Round 1
// baseline (1020.169 us; speedup 1.0000x reference)
//
#include <hip/hip_runtime.h>
#include <hip/hip_bf16.h>

#define N_FULL 200000
#define N_SUB  80000
#define E_NUM  800000
#define IN_DIM 128
#define HD     128
#define LMAX   5

#define NB_SCAN ((N_SUB + 255) / 256)   // 313

// ---------------- CSR build ----------------

__global__ void zero_counts(int* __restrict__ cnt, int* __restrict__ cursor) {
    int i = blockIdx.x * blockDim.x + threadIdx.x;
    if (i < N_SUB) { cnt[i] = 0; cursor[i] = 0; }
}

__global__ void count_deg(const int* __restrict__ dst, int* __restrict__ cnt) {
    int i = blockIdx.x * blockDim.x + threadIdx.x;
    if (i < E_NUM) atomicAdd(&cnt[dst[i]], 1);
}

__global__ void scan_block(const int* __restrict__ cnt, int* __restrict__ offs,
                           int* __restrict__ bsums) {
    __shared__ int s[256];
    int t = threadIdx.x;
    int i = blockIdx.x * 256 + t;
    int v = (i < N_SUB) ? cnt[i] : 0;
    s[t] = v;
    __syncthreads();
    for (int off = 1; off < 256; off <<= 1) {
        int x = (t >= off) ? s[t - off] : 0;
        __syncthreads();
        s[t] += x;
        __syncthreads();
    }
    if (i < N_SUB) offs[i] = s[t] - v;          // exclusive within block
    if (t == 255) bsums[blockIdx.x] = s[255];   // block total
}

__global__ void scan_sums(int* __restrict__ bsums) {
    __shared__ int s[512];
    int t = threadIdx.x;
    int v = (t < NB_SCAN) ? bsums[t] : 0;
    s[t] = v;
    __syncthreads();
    for (int off = 1; off < 512; off <<= 1) {
        int x = (t >= off) ? s[t - off] : 0;
        __syncthreads();
        s[t] += x;
        __syncthreads();
    }
    if (t < NB_SCAN) bsums[t] = s[t] - v;       // exclusive
}

__global__ void scan_add(int* __restrict__ offs, const int* __restrict__ bsums) {
    int i = blockIdx.x * 256 + threadIdx.x;
    if (i < N_SUB) offs[i] += bsums[blockIdx.x];
    if (i == 0) offs[N_SUB] = E_NUM;
}

__global__ void fill_csr(const int* __restrict__ src, const int* __restrict__ dst,
                         const int* __restrict__ offs, int* __restrict__ cursor,
                         int* __restrict__ csr) {
    int i = blockIdx.x * blockDim.x + threadIdx.x;
    if (i < E_NUM) {
        int d = dst[i];
        int p = atomicAdd(&cursor[d], 1);
        csr[offs[d] + p] = src[i];
    }
}

// ---------------- mean aggregation (gather via CSR) ----------------

__global__ __launch_bounds__(256) void aggregate(
    const float* __restrict__ H, float* __restrict__ Out,
    const int* __restrict__ offs, const int* __restrict__ csr,
    const int* __restrict__ cnt) {
    int node = blockIdx.x * 4 + (threadIdx.x >> 6);
    if (node >= N_SUB) return;
    int lane = threadIdx.x & 63;
    int beg = offs[node], end = offs[node + 1];
    float ax = 0.f, ay = 0.f;
    for (int j = beg; j < end; ++j) {
        int s = csr[j];   // uniform across wave -> scalar load
        float2 v = *(const float2*)(H + (size_t)s * HD + lane * 2);
        ax += v.x; ay += v.y;
    }
    int c = cnt[node];
    float inv = 1.0f / (float)(c > 1 ? c : 1);
    *(float2*)(Out + (size_t)node * HD + lane * 2) = make_float2(ax * inv, ay * inv);
}

// ---------------- fp32 tiled GEMM ----------------
// Out[row][f] = act( sum_k A1[row][k]*W1[f][k] (+ sum_k A2[row][k]*W2[f][k]) + bias[f] )
// A gathered via `gather` if non-null (proj). N=128 fixed, K=128 per A-source.
// Block tile: 64 rows x 128 cols, 256 threads, thread tile 4x8.

#define GBM 64
#define GBK 32

__global__ __launch_bounds__(256) void gemm_sage(
    const float* __restrict__ A1, const float* __restrict__ A2,
    const float* __restrict__ W1, const float* __restrict__ W2,
    const float* __restrict__ bias, float* __restrict__ Out,
    const int* __restrict__ gather, int M, int do_relu) {

    __shared__ __align__(16) float As[GBK][68];   // [k][m], padded stride (272B, 16B-aligned rows)
    __shared__ __align__(16) float Ws[GBK][132];  // [k][n], padded stride (528B)

    int tid = threadIdx.x;
    int row0 = blockIdx.x * GBM;
    int tx = tid & 15, ty = tid >> 4;
    int r0 = ty * 4;          // 4 consecutive rows
    int c0 = tx * 4;          // cols c0..c0+3 and c0+64..c0+67

    float acc[4][8];
#pragma unroll
    for (int i = 0; i < 4; ++i)
#pragma unroll
        for (int j = 0; j < 8; ++j) acc[i][j] = 0.f;

    int nchunk = A2 ? 8 : 4;
    for (int ch = 0; ch < nchunk; ++ch) {
        const float* Asrc = (ch < 4) ? A1 : A2;
        const float* Wsrc = (ch < 4) ? W1 : W2;
        int kbase = (ch & 3) * GBK;

        // stage A tile (64 rows x 32 k), transposed into As[k][m]
#pragma unroll
        for (int it = 0; it < 2; ++it) {
            int idx = tid + it * 256;
            int m = idx >> 3, kq = idx & 7;
            int row = row0 + m;
            float4 v = make_float4(0.f, 0.f, 0.f, 0.f);
            if (row < M) {
                int gr = gather ? gather[row] : row;
                v = *(const float4*)(Asrc + (size_t)gr * 128 + kbase + kq * 4);
            }
            As[kq * 4 + 0][m] = v.x;
            As[kq * 4 + 1][m] = v.y;
            As[kq * 4 + 2][m] = v.z;
            As[kq * 4 + 3][m] = v.w;
        }
        // stage W tile (128 n x 32 k), transposed into Ws[k][n]
#pragma unroll
        for (int it = 0; it < 4; ++it) {
            int idx = tid + it * 256;
            int n = idx >> 3, kq = idx & 7;
            float4 v = *(const float4*)(Wsrc + n * 128 + kbase + kq * 4);
            Ws[kq * 4 + 0][n] = v.x;
            Ws[kq * 4 + 1][n] = v.y;
            Ws[kq * 4 + 2][n] = v.z;
            Ws[kq * 4 + 3][n] = v.w;
        }
        __syncthreads();

#pragma unroll
        for (int kk = 0; kk < GBK; ++kk) {
            float4 a  = *(const float4*)&As[kk][r0];
            float4 w0 = *(const float4*)&Ws[kk][c0];
            float4 w1 = *(const float4*)&Ws[kk][c0 + 64];
            float av[4] = {a.x, a.y, a.z, a.w};
            float wv[8] = {w0.x, w0.y, w0.z, w0.w, w1.x, w1.y, w1.z, w1.w};
#pragma unroll
            for (int i = 0; i < 4; ++i)
#pragma unroll
                for (int j = 0; j < 8; ++j)
                    acc[i][j] = fmaf(av[i], wv[j], acc[i][j]);
        }
        __syncthreads();
    }

    // epilogue
#pragma unroll
    for (int i = 0; i < 4; ++i) {
        int row = row0 + r0 + i;
        if (row >= M) continue;
        float4 o0, o1;
        o0.x = acc[i][0] + bias[c0 + 0];
        o0.y = acc[i][1] + bias[c0 + 1];
        o0.z = acc[i][2] + bias[c0 + 2];
        o0.w = acc[i][3] + bias[c0 + 3];
        o1.x = acc[i][4] + bias[c0 + 64];
        o1.y = acc[i][5] + bias[c0 + 65];
        o1.z = acc[i][6] + bias[c0 + 66];
        o1.w = acc[i][7] + bias[c0 + 67];
        if (do_relu) {
            o0.x = fmaxf(o0.x, 0.f); o0.y = fmaxf(o0.y, 0.f);
            o0.z = fmaxf(o0.z, 0.f); o0.w = fmaxf(o0.w, 0.f);
            o1.x = fmaxf(o1.x, 0.f); o1.y = fmaxf(o1.y, 0.f);
            o1.z = fmaxf(o1.z, 0.f); o1.w = fmaxf(o1.w, 0.f);
        }
        *(float4*)(Out + (size_t)row * 128 + c0) = o0;
        *(float4*)(Out + (size_t)row * 128 + c0 + 64) = o1;
    }
}

// ---------------- head MLP on nodes 0,1 ----------------

__global__ void head_kernel(const float* __restrict__ H,
                            const float* __restrict__ W_e1, const float* __restrict__ b_e1,
                            const float* __restrict__ W_e2, const float* __restrict__ b_e2,
                            const float* __restrict__ W_h1, const float* __restrict__ b_h1,
                            const float* __restrict__ W_h2, const float* __restrict__ b_h2,
                            float* __restrict__ head_out, int kidx) {
    __shared__ float hu[128], hv[128], red[2];
    __shared__ float sc_sh;
    int t = threadIdx.x;
    hu[t] = H[t];
    hv[t] = H[128 + t];
    __syncthreads();

    float accv = b_e1[t];
    const float* wr = W_e1 + t * 384;
    for (int k2 = 0; k2 < 128; ++k2) {
        float a = hu[k2], b = hv[k2];
        accv += a * wr[k2] + b * wr[128 + k2] + a * b * wr[256 + k2];
    }
    float v = fmaxf(accv, 0.f) * W_e2[t];
    for (int off = 32; off; off >>= 1) v += __shfl_down(v, off);
    if ((t & 63) == 0) red[t >> 6] = v;
    __syncthreads();
    if (t == 0) sc_sh = red[0] + red[1] + b_e2[0];
    __syncthreads();
    float score = sc_sh;

    if (t < 64) {
        float a2 = b_h1[t];
        const float* wh = W_h1 + t * 257;
        for (int k2 = 0; k2 < 128; ++k2)
            a2 += hu[k2] * wh[k2] + hv[k2] * wh[128 + k2];
        a2 += score * wh[256];
        float g = fmaxf(a2, 0.f) * W_h2[t];
        for (int off = 32; off; off >>= 1) g += __shfl_down(g, off);
        if (t == 0) {
            float p = 1.f / (1.f + expf(-(g + b_h2[0])));
            head_out[kidx * 2 + 0] = score;
            head_out[kidx * 2 + 1] = p;
        }
    }
}

__global__ void finalize(const float* __restrict__ head_out, float* __restrict__ out) {
    if (threadIdx.x == 0 && blockIdx.x == 0) {
        float a[LMAX];
        float p_not = 1.f, s = 0.f;
        for (int k = 0; k < LMAX; ++k) {
            float p = head_out[2 * k + 1];
            a[k] = p * p_not;
            p_not *= (1.f - p);
            s += a[k];
        }
        float inv = 1.f / (s + 1e-8f);
        float fs = 0.f, ed = 0.f;
        for (int k = 0; k < LMAX; ++k) {
            float al = a[k] * inv;
            out[2 + k] = al;
            fs += al * head_out[2 * k];
            ed += al * (float)(k + 1);
        }
        out[0] = fs;
        out[1] = ed;
    }
}

// ---------------- launch ----------------

extern "C" void kernel_launch(void* const* d_in, const int* in_sizes, int n_in,
                              void* d_out, int out_size, void* d_ws, size_t ws_size,
                              hipStream_t stream) {
    const float* x_full = (const float*)d_in[0];
    const float* W_in  = (const float*)d_in[1];
    const float* b_in  = (const float*)d_in[2];
    const float* W_l   = (const float*)d_in[3];
    const float* b_l   = (const float*)d_in[4];
    const float* W_r   = (const float*)d_in[5];
    const float* W_e1  = (const float*)d_in[6];
    const float* b_e1  = (const float*)d_in[7];
    const float* W_e2  = (const float*)d_in[8];
    const float* b_e2  = (const float*)d_in[9];
    const float* W_h1  = (const float*)d_in[10];
    const float* b_h1  = (const float*)d_in[11];
    const float* W_h2  = (const float*)d_in[12];
    const float* b_h2  = (const float*)d_in[13];
    const int* subset  = (const int*)d_in[14];
    const int* edge    = (const int*)d_in[15];
    const int* esrc = edge;
    const int* edst = edge + E_NUM;

    // workspace carve-up (~86.5 MB total)
    char* w = (char*)d_ws;
    float* HA = (float*)w;      w += (size_t)N_SUB * HD * 4;   // 40.96 MB
    float* HB = (float*)w;      w += (size_t)N_SUB * HD * 4;   // 40.96 MB
    int* cnt = (int*)w;         w += (size_t)N_SUB * 4;
    int* offs = (int*)w;        w += (size_t)(N_SUB + 64) * 4;
    int* cursor = (int*)w;      w += (size_t)N_SUB * 4;
    int* csr = (int*)w;         w += (size_t)E_NUM * 4;        // 3.2 MB
    int* bsums = (int*)w;       w += 4096;
    float* head_out = (float*)w; w += 256;

    // CSR build
    zero_counts<<<(N_SUB + 255) / 256, 256, 0, stream>>>(cnt, cursor);
    count_deg<<<(E_NUM + 255) / 256, 256, 0, stream>>>(edst, cnt);
    scan_block<<<NB_SCAN, 256, 0, stream>>>(cnt, offs, bsums);
    scan_sums<<<1, 512, 0, stream>>>(bsums);
    scan_add<<<NB_SCAN, 256, 0, stream>>>(offs, bsums);
    fill_csr<<<(E_NUM + 255) / 256, 256, 0, stream>>>(esrc, edst, offs, cursor, csr);

    // input projection: HA = x_full[subset] @ W_in.T + b_in
    gemm_sage<<<(N_SUB + GBM - 1) / GBM, 256, 0, stream>>>(
        x_full, nullptr, W_in, nullptr, b_in, HA, subset, N_SUB, 0);

    for (int k = 0; k < LMAX; ++k) {
        aggregate<<<(N_SUB + 3) / 4, 256, 0, stream>>>(HA, HB, offs, csr, cnt);
        // HA = relu(HB @ W_l.T + b_l + HA @ W_r.T)   (in-place safe: per-block rows)
        gemm_sage<<<(N_SUB + GBM - 1) / GBM, 256, 0, stream>>>(
            HB, HA, W_l, W_r, b_l, HA, nullptr, N_SUB, 1);
        head_kernel<<<1, 128, 0, stream>>>(HA, W_e1, b_e1, W_e2, b_e2,
                                           W_h1, b_h1, W_h2, b_h2, head_out, k);
    }
    finalize<<<1, 1, 0, stream>>>(head_out, (float*)d_out);
}